// Round 2
// baseline (757.663 us; speedup 1.0000x reference)
//
#include <hip/hip_runtime.h>

#define C_ 256
#define B_ 32
#define HW_ 3136
#define M_ 100352
#define NCHUNK_ 256
#define CHM_ 392
#define EPSV 1e-5f

// ---------------- K1: partial Gram + per-channel sums ----------------
// grid 256 x 1024 threads. Each block: 392 columns of x (one (b, hw-range) chunk),
// full 256x256 partial Gram in registers (8x8 per thread, 32x32 thread grid).
__global__ __launch_bounds__(1024) void k_gram(const float* __restrict__ X,
        float* __restrict__ pG, float* __restrict__ psum, float* __restrict__ pdiag,
        int NP, int atomic_mode) {
    __shared__ __align__(16) float xt[32][260];
    const int tid = threadIdx.x;
    const int i = tid >> 5, j = tid & 31;
    float acc[8][8];
#pragma unroll
    for (int r = 0; r < 8; ++r)
#pragma unroll
        for (int s = 0; s < 8; ++s) acc[r][s] = 0.f;
    float csum = 0.f;

    for (int chunk = blockIdx.x; chunk < NCHUNK_; chunk += gridDim.x) {
        const int b = chunk >> 3;
        const int hw0 = (chunk & 7) * CHM_;
        const float* Xb = X + (size_t)b * C_ * HW_ + hw0;
        for (int k0 = 0; k0 < CHM_; k0 += 32) {
            const int klen = (CHM_ - k0) >= 32 ? 32 : (CHM_ - k0);  // 32 or 8
            __syncthreads();
            if (klen == 32) {
                for (int idx = tid; idx < 32 * C_; idx += 1024) {
                    int kk = idx & 31, c = idx >> 5;
                    xt[kk][c] = Xb[(size_t)c * HW_ + k0 + kk];
                }
            } else {
                for (int idx = tid; idx < 8 * C_; idx += 1024) {
                    int kk = idx & 7, c = idx >> 3;
                    xt[kk][c] = Xb[(size_t)c * HW_ + k0 + kk];
                }
            }
            __syncthreads();
            if (tid < C_) {
                float s = 0.f;
                for (int kk = 0; kk < klen; ++kk) s += xt[kk][tid];
                csum += s;
            }
#pragma unroll 4
            for (int kk = 0; kk < klen; ++kk) {
                float a[8], bb[8];
                *(float4*)&a[0]  = *(const float4*)&xt[kk][8 * i];
                *(float4*)&a[4]  = *(const float4*)&xt[kk][8 * i + 4];
                *(float4*)&bb[0] = *(const float4*)&xt[kk][8 * j];
                *(float4*)&bb[4] = *(const float4*)&xt[kk][8 * j + 4];
#pragma unroll
                for (int r = 0; r < 8; ++r)
#pragma unroll
                    for (int s = 0; s < 8; ++s) acc[r][s] += a[r] * bb[s];
            }
        }
    }

    const int p = atomic_mode ? (blockIdx.x % NP) : blockIdx.x;
    float* og = pG + (size_t)p * 65536 + (8 * i) * 256 + 8 * j;
    if (!atomic_mode) {
#pragma unroll
        for (int r = 0; r < 8; ++r) {
            *(float4*)&og[r * 256]     = make_float4(acc[r][0], acc[r][1], acc[r][2], acc[r][3]);
            *(float4*)&og[r * 256 + 4] = make_float4(acc[r][4], acc[r][5], acc[r][6], acc[r][7]);
        }
        if (tid < C_) psum[p * C_ + tid] = csum;
        if (i == j) {
#pragma unroll
            for (int r = 0; r < 8; ++r) pdiag[p * C_ + 8 * i + r] = acc[r][r];
        }
    } else {
#pragma unroll
        for (int r = 0; r < 8; ++r)
#pragma unroll
            for (int s = 0; s < 8; ++s) atomicAdd(&og[r * 256 + s], acc[r][s]);
        if (tid < C_) atomicAdd(&psum[p * C_ + tid], csum);
        if (i == j) {
#pragma unroll
            for (int r = 0; r < 8; ++r) atomicAdd(&pdiag[p * C_ + 8 * i + r], acc[r][r]);
        }
    }
}

// ---------------- K2: mean, trace, rTr ----------------
__global__ __launch_bounds__(256) void k_stats(const float* __restrict__ psum,
        const float* __restrict__ pdiag, float* __restrict__ mean,
        float* __restrict__ scal, int NP) {
    __shared__ float red[256];
    const int c = threadIdx.x;
    float s = 0.f, d = 0.f;
    for (int p = 0; p < NP; ++p) { s += psum[p * C_ + c]; d += pdiag[p * C_ + c]; }
    const float mn = s * (1.f / (float)M_);
    mean[c] = mn;
    red[c] = d * (1.f / (float)M_) - mn * mn + EPSV;   // Sigma[c][c]
    __syncthreads();
    for (int off = 128; off > 0; off >>= 1) {
        if (c < off) red[c] += red[c + off];
        __syncthreads();
    }
    if (c == 0) {
        float rTr = 1.f / red[0];
        scal[0] = rTr;
        scal[1] = sqrtf(rTr);
    }
}

// ---------------- K3: assemble Sigma_N and P1 (first NS iter is exact: P1 = 1.5I - 0.5*SigN)
__global__ __launch_bounds__(1024) void k_sigma(const float* __restrict__ pG,
        const float* __restrict__ mean, const float* __restrict__ scal,
        float* __restrict__ SigN, float* __restrict__ P, int NP) {
    const int e = blockIdx.x * 1024 + threadIdx.x;
    const int r = e >> 8, c = e & 255;
    float s = 0.f;
    for (int p = 0; p < NP; ++p) s += pG[(size_t)p * 65536 + e];
    float sig = s * (1.f / (float)M_) - mean[r] * mean[c] + ((r == c) ? EPSV : 0.f);
    float sn = sig * scal[0];
    SigN[e] = sn;
    P[e] = ((r == c) ? 1.5f : 0.f) - 0.5f * sn;
}

// ---------------- small 256x256 matmul, 64 blocks x 256 thr, 2x2/thread ----------------
// MODE 0: D = A*B          MODE 1: D = 1.5*aux - 0.5*(A*B)  (in-place NS update)
// MODE 2: D^T = aux[1]*(A*B)  (writes transposed M, scaled by sqrt(rTr))
template <int MODE>
__global__ __launch_bounds__(256) void k_mm(const float* __restrict__ A,
        const float* __restrict__ Bm, float* __restrict__ D, const float* __restrict__ aux) {
    __shared__ __align__(16) float Ast[256][34];  // Ast[k][r] = A[32bi+r][k]
    __shared__ __align__(16) float Bs[256][34];   // Bs[k][c]  = B[k][32bj+c]
    const int tid = threadIdx.x;
    const int bi = blockIdx.x >> 3, bj = blockIdx.x & 7;
    const int i2 = tid >> 4, j2 = tid & 15;
#pragma unroll 4
    for (int s = 0; s < 32; ++s) {
        Ast[tid][s] = A[(32 * bi + s) * 256 + tid];
        int k = s * 8 + (tid >> 5), cc = tid & 31;
        Bs[k][cc] = Bm[k * 256 + 32 * bj + cc];
    }
    __syncthreads();
    float a00 = 0.f, a01 = 0.f, a10 = 0.f, a11 = 0.f;
#pragma unroll 8
    for (int k = 0; k < 256; ++k) {
        float2 av = *(const float2*)&Ast[k][2 * i2];
        float2 bv = *(const float2*)&Bs[k][2 * j2];
        a00 += av.x * bv.x; a01 += av.x * bv.y;
        a10 += av.y * bv.x; a11 += av.y * bv.y;
    }
    const int row = 32 * bi + 2 * i2, col = 32 * bj + 2 * j2;
    if (MODE == 0) {
        D[row * 256 + col] = a00;       D[row * 256 + col + 1] = a01;
        D[(row + 1) * 256 + col] = a10; D[(row + 1) * 256 + col + 1] = a11;
    } else if (MODE == 1) {
        int e0 = row * 256 + col, e1 = e0 + 256;
        D[e0]     = 1.5f * aux[e0]     - 0.5f * a00;
        D[e0 + 1] = 1.5f * aux[e0 + 1] - 0.5f * a01;
        D[e1]     = 1.5f * aux[e1]     - 0.5f * a10;
        D[e1 + 1] = 1.5f * aux[e1 + 1] - 0.5f * a11;
    } else {
        const float sc = aux[1];
        D[col * 256 + row]           = sc * a00;
        D[(col + 1) * 256 + row]     = sc * a01;
        D[col * 256 + row + 1]       = sc * a10;
        D[(col + 1) * 256 + row + 1] = sc * a11;
    }
}

// ---------------- K6: beta[d] = bias[d] - weight[d] * (M·mean)[d] ----------------
__global__ __launch_bounds__(256) void k_beta(const float* __restrict__ Mt,
        const float* __restrict__ mean, const float* __restrict__ weight,
        const float* __restrict__ bias, float* __restrict__ beta) {
    const int d = threadIdx.x;
    float s = 0.f;
    for (int c = 0; c < C_; ++c) s += Mt[c * 256 + d] * mean[c];
    beta[d] = bias[d] - weight[d] * s;
}

// ---------------- K7: out[b,d,hw] = weight[d]*sum_c M[d,c]*X[b,c,hw] + beta[d] ----------------
// grid 1568 (32 b x 49 hw-tiles of 64), 256 thr, out-tile 256x64, 8x8/thread.
__global__ __launch_bounds__(256) void k_out(const float* __restrict__ X,
        const float* __restrict__ Mt, const float* __restrict__ weight,
        const float* __restrict__ beta, float* __restrict__ out) {
    __shared__ __align__(16) float Ms[32][260];  // Ms[kk][d] = Mt[c0+kk][d]
    __shared__ __align__(16) float xs[32][68];   // xs[kk][mm]
    const int tid = threadIdx.x;
    const int bk = blockIdx.x;
    const int b = bk / 49;
    const int hw0 = (bk - b * 49) * 64;
    const int i = tid >> 3, j = tid & 7;
    const float* Xb = X + (size_t)b * C_ * HW_ + hw0;
    float acc[8][8];
#pragma unroll
    for (int r = 0; r < 8; ++r)
#pragma unroll
        for (int s = 0; s < 8; ++s) acc[r][s] = 0.f;

    for (int c0 = 0; c0 < C_; c0 += 32) {
        __syncthreads();
#pragma unroll 4
        for (int s = 0; s < 32; ++s) Ms[s][tid] = Mt[(c0 + s) * 256 + tid];
#pragma unroll
        for (int s = 0; s < 8; ++s) {
            int idx = s * 256 + tid;
            int kk = idx >> 6, mm = idx & 63;
            xs[kk][mm] = Xb[(size_t)(c0 + kk) * HW_ + mm];
        }
        __syncthreads();
#pragma unroll 2
        for (int kk = 0; kk < 32; ++kk) {
            float a[8], bb[8];
            *(float4*)&a[0]  = *(const float4*)&Ms[kk][8 * i];
            *(float4*)&a[4]  = *(const float4*)&Ms[kk][8 * i + 4];
            *(float4*)&bb[0] = *(const float4*)&xs[kk][8 * j];
            *(float4*)&bb[4] = *(const float4*)&xs[kk][8 * j + 4];
#pragma unroll
            for (int r = 0; r < 8; ++r)
#pragma unroll
                for (int s = 0; s < 8; ++s) acc[r][s] += a[r] * bb[s];
        }
    }

    float* ob = out + (size_t)b * C_ * HW_ + hw0;
#pragma unroll
    for (int r = 0; r < 8; ++r) {
        int d = 8 * i + r;
        float w = weight[d], be = beta[d];
        float4 v0 = make_float4(w * acc[r][0] + be, w * acc[r][1] + be,
                                w * acc[r][2] + be, w * acc[r][3] + be);
        float4 v1 = make_float4(w * acc[r][4] + be, w * acc[r][5] + be,
                                w * acc[r][6] + be, w * acc[r][7] + be);
        *(float4*)&ob[(size_t)d * HW_ + 8 * j]     = v0;
        *(float4*)&ob[(size_t)d * HW_ + 8 * j + 4] = v1;
    }
}

extern "C" void kernel_launch(void* const* d_in, const int* in_sizes, int n_in,
                              void* d_out, int out_size, void* d_ws, size_t ws_size,
                              hipStream_t stream) {
    const float* X      = (const float*)d_in[0];
    const float* rot    = (const float*)d_in[1];
    const float* weight = (const float*)d_in[2];
    const float* bias   = (const float*)d_in[3];
    float* out = (float*)d_out;
    float* wsf = (float*)d_ws;

    float* SigN = wsf;
    float* P    = wsf + 65536;
    float* P2   = wsf + 2 * 65536;
    float* P3   = wsf + 3 * 65536;
    float* Mt   = wsf + 4 * 65536;
    float* mean = wsf + 5 * 65536;
    float* beta = mean + 256;
    float* scal = mean + 512;
    float* psum = mean + 768;

    long avail = (long)(ws_size / 4) - (5L * 65536 + 768);
    int NP = (int)(avail / (65536 + 512));
    int atomic_mode = 0;
    if (NP >= 256) {
        NP = 256;
    } else {
        if (NP < 1) NP = 1;
        atomic_mode = 1;
    }
    float* pdiag = psum + (size_t)NP * 256;
    float* pG    = pdiag + (size_t)NP * 256;

    if (atomic_mode) {
        hipMemsetAsync(psum, 0, ((size_t)NP * 512 + (size_t)NP * 65536) * 4, stream);
    }

    k_gram<<<256, 1024, 0, stream>>>(X, pG, psum, pdiag, NP, atomic_mode);
    k_stats<<<1, 256, 0, stream>>>(psum, pdiag, mean, scal, NP);
    k_sigma<<<64, 1024, 0, stream>>>(pG, mean, scal, SigN, P, NP);
    for (int it = 0; it < 4; ++it) {
        k_mm<0><<<64, 256, 0, stream>>>(P,  P,    P2, scal);
        k_mm<0><<<64, 256, 0, stream>>>(P2, P,    P3, scal);
        k_mm<1><<<64, 256, 0, stream>>>(P3, SigN, P,  P);
    }
    k_mm<2><<<64, 256, 0, stream>>>(rot, P, Mt, scal);
    k_beta<<<1, 256, 0, stream>>>(Mt, mean, weight, bias, beta);
    k_out<<<1568, 256, 0, stream>>>(X, Mt, weight, beta, out);
}

// Round 3
// 719.435 us; speedup vs baseline: 1.0531x; 1.0531x over previous
//
#include <hip/hip_runtime.h>

#define C_ 256
#define B_ 32
#define HW_ 3136
#define M_ 100352
#define NCHUNK_ 256
#define CHM_ 392
#define EPSV 1e-5f

// ---------------- K1: partial Gram + per-channel sums ----------------
// grid 256 x 1024 threads. Each block: 392 columns of x (one (b, hw-range) chunk),
// full 256x256 partial Gram in registers. Thread (i,j) owns rows 8i..8i+7,
// cols {4j..4j+3} U {128+4j..131+4j}  (contiguous float4 b-reads -> no bank conflict).
__global__ __launch_bounds__(1024) void k_gram(const float* __restrict__ X,
        float* __restrict__ pG, float* __restrict__ psum, float* __restrict__ pdiag,
        int NP, int atomic_mode) {
    __shared__ __align__(16) float xt[32][260];
    const int tid = threadIdx.x;
    const int i = tid >> 5, j = tid & 31;
    float acc[8][8];
#pragma unroll
    for (int r = 0; r < 8; ++r)
#pragma unroll
        for (int s = 0; s < 8; ++s) acc[r][s] = 0.f;
    float csum = 0.f, cdiag = 0.f;

    for (int chunk = blockIdx.x; chunk < NCHUNK_; chunk += gridDim.x) {
        const int b = chunk >> 3;
        const int hw0 = (chunk & 7) * CHM_;
        const float* Xb = X + (size_t)b * C_ * HW_ + hw0;
        for (int k0 = 0; k0 < CHM_; k0 += 32) {
            const int klen = (CHM_ - k0) >= 32 ? 32 : (CHM_ - k0);  // 32 or 8
            __syncthreads();
            if (klen == 32) {
                for (int idx = tid; idx < 32 * C_; idx += 1024) {
                    int kk = idx & 31, c = idx >> 5;
                    xt[kk][c] = Xb[(size_t)c * HW_ + k0 + kk];
                }
            } else {
                for (int idx = tid; idx < 8 * C_; idx += 1024) {
                    int kk = idx & 7, c = idx >> 3;
                    xt[kk][c] = Xb[(size_t)c * HW_ + k0 + kk];
                }
            }
            __syncthreads();
            if (tid < C_) {
                float s = 0.f, q = 0.f;
                for (int kk = 0; kk < klen; ++kk) { float v = xt[kk][tid]; s += v; q += v * v; }
                csum += s; cdiag += q;
            }
#pragma unroll 4
            for (int kk = 0; kk < klen; ++kk) {
                float a[8], bb[8];
                *(float4*)&a[0]  = *(const float4*)&xt[kk][8 * i];
                *(float4*)&a[4]  = *(const float4*)&xt[kk][8 * i + 4];
                *(float4*)&bb[0] = *(const float4*)&xt[kk][4 * j];
                *(float4*)&bb[4] = *(const float4*)&xt[kk][128 + 4 * j];
#pragma unroll
                for (int r = 0; r < 8; ++r)
#pragma unroll
                    for (int s = 0; s < 8; ++s) acc[r][s] += a[r] * bb[s];
            }
        }
    }

    const int p = atomic_mode ? (blockIdx.x % NP) : blockIdx.x;
    float* og = pG + (size_t)p * 65536 + (8 * i) * 256;
    if (!atomic_mode) {
#pragma unroll
        for (int r = 0; r < 8; ++r) {
            *(float4*)&og[r * 256 + 4 * j]       = make_float4(acc[r][0], acc[r][1], acc[r][2], acc[r][3]);
            *(float4*)&og[r * 256 + 128 + 4 * j] = make_float4(acc[r][4], acc[r][5], acc[r][6], acc[r][7]);
        }
        if (tid < C_) { psum[p * C_ + tid] = csum; pdiag[p * C_ + tid] = cdiag; }
    } else {
#pragma unroll
        for (int r = 0; r < 8; ++r)
#pragma unroll
            for (int s = 0; s < 8; ++s) {
                int col = (s < 4) ? (4 * j + s) : (128 + 4 * j + s - 4);
                atomicAdd(&og[r * 256 + col], acc[r][s]);
            }
        if (tid < C_) { atomicAdd(&psum[p * C_ + tid], csum); atomicAdd(&pdiag[p * C_ + tid], cdiag); }
    }
}

// ---------------- K2: mean, trace, rTr ----------------
__global__ __launch_bounds__(256) void k_stats(const float* __restrict__ psum,
        const float* __restrict__ pdiag, float* __restrict__ mean,
        float* __restrict__ scal, int NP) {
    __shared__ float red[256];
    const int c = threadIdx.x;
    float s = 0.f, d = 0.f;
    for (int p = 0; p < NP; ++p) { s += psum[p * C_ + c]; d += pdiag[p * C_ + c]; }
    const float mn = s * (1.f / (float)M_);
    mean[c] = mn;
    red[c] = d * (1.f / (float)M_) - mn * mn + EPSV;   // Sigma[c][c]
    __syncthreads();
    for (int off = 128; off > 0; off >>= 1) {
        if (c < off) red[c] += red[c + off];
        __syncthreads();
    }
    if (c == 0) {
        float rTr = 1.f / red[0];
        scal[0] = rTr;
        scal[1] = sqrtf(rTr);
    }
}

// ---------------- K3: assemble Sigma_N and P1 (first NS iter exact: P1 = 1.5I - 0.5*SigN)
__global__ __launch_bounds__(1024) void k_sigma(const float* __restrict__ pG,
        const float* __restrict__ mean, const float* __restrict__ scal,
        float* __restrict__ SigN, float* __restrict__ P, int NP) {
    const int e = blockIdx.x * 1024 + threadIdx.x;
    const int r = e >> 8, c = e & 255;
    float s = 0.f;
    for (int p = 0; p < NP; ++p) s += pG[(size_t)p * 65536 + e];
    float sig = s * (1.f / (float)M_) - mean[r] * mean[c] + ((r == c) ? EPSV : 0.f);
    float sn = sig * scal[0];
    SigN[e] = sn;
    P[e] = ((r == c) ? 1.5f : 0.f) - 0.5f * sn;
}

// ---------------- small 256x256 matmul bodies ----------------
__device__ __forceinline__ void mm_body(const float* __restrict__ A,
        const float* __restrict__ Bm, int blk, int tid,
        float& a00, float& a01, float& a10, float& a11, int& row, int& col) {
    __shared__ __align__(16) float Ast[256][34];  // Ast[k][r] = A[32bi+r][k]
    __shared__ __align__(16) float Bs[256][34];   // Bs[k][c]  = B[k][32bj+c]
    const int bi = blk >> 3, bj = blk & 7;
    const int i2 = tid >> 4, j2 = tid & 15;
#pragma unroll 4
    for (int s = 0; s < 32; ++s) {
        Ast[tid][s] = A[(32 * bi + s) * 256 + tid];
        int k = s * 8 + (tid >> 5), cc = tid & 31;
        Bs[k][cc] = Bm[k * 256 + 32 * bj + cc];
    }
    __syncthreads();
    a00 = 0.f; a01 = 0.f; a10 = 0.f; a11 = 0.f;
#pragma unroll 8
    for (int k = 0; k < 256; ++k) {
        float2 av = *(const float2*)&Ast[k][2 * i2];
        float2 bv = *(const float2*)&Bs[k][2 * j2];
        a00 += av.x * bv.x; a01 += av.x * bv.y;
        a10 += av.y * bv.x; a11 += av.y * bv.y;
    }
    row = 32 * bi + 2 * i2; col = 32 * bj + 2 * j2;
}

// pair launch: blocks 0-63: D1 = A1*B1; blocks 64-127: D2 = A2*B2
__global__ __launch_bounds__(256) void k_mm_pair(const float* __restrict__ A1,
        const float* __restrict__ B1, float* __restrict__ D1,
        const float* __restrict__ A2, const float* __restrict__ B2, float* __restrict__ D2) {
    const int second = blockIdx.x >> 6;
    const float* A = second ? A2 : A1;
    const float* Bm = second ? B2 : B1;
    float* D = second ? D2 : D1;
    float a00, a01, a10, a11; int row, col;
    mm_body(A, Bm, blockIdx.x & 63, threadIdx.x, a00, a01, a10, a11, row, col);
    D[row * 256 + col] = a00;       D[row * 256 + col + 1] = a01;
    D[(row + 1) * 256 + col] = a10; D[(row + 1) * 256 + col + 1] = a11;
}

// NS update: P = 1.5*P - 0.5*(A*B)
__global__ __launch_bounds__(256) void k_mm_upd(const float* __restrict__ A,
        const float* __restrict__ Bm, float* __restrict__ P) {
    float a00, a01, a10, a11; int row, col;
    mm_body(A, Bm, blockIdx.x, threadIdx.x, a00, a01, a10, a11, row, col);
    int e0 = row * 256 + col, e1 = e0 + 256;
    P[e0]     = 1.5f * P[e0]     - 0.5f * a00;
    P[e0 + 1] = 1.5f * P[e0 + 1] - 0.5f * a01;
    P[e1]     = 1.5f * P[e1]     - 0.5f * a10;
    P[e1 + 1] = 1.5f * P[e1 + 1] - 0.5f * a11;
}

// final: Mt = sqrt(rTr) * (rot*P)^T   (Mt[c][d] = M[d][c])
__global__ __launch_bounds__(256) void k_mm_rot(const float* __restrict__ A,
        const float* __restrict__ Bm, float* __restrict__ D, const float* __restrict__ scal) {
    float a00, a01, a10, a11; int row, col;
    mm_body(A, Bm, blockIdx.x, threadIdx.x, a00, a01, a10, a11, row, col);
    const float sc = scal[1];
    D[col * 256 + row]           = sc * a00;
    D[(col + 1) * 256 + row]     = sc * a01;
    D[col * 256 + row + 1]       = sc * a10;
    D[(col + 1) * 256 + row + 1] = sc * a11;
}

// ---------------- K6: beta[d] = bias[d] - weight[d] * (M·mean)[d] ----------------
__global__ __launch_bounds__(256) void k_beta(const float* __restrict__ Mt,
        const float* __restrict__ mean, const float* __restrict__ weight,
        const float* __restrict__ bias, float* __restrict__ beta) {
    const int d = threadIdx.x;
    float s = 0.f;
    for (int c = 0; c < C_; ++c) s += Mt[c * 256 + d] * mean[c];
    beta[d] = bias[d] - weight[d] * s;
}

// ---------------- K7: out[b,d,hw] = weight[d]*sum_c M[d,c]*X[b,c,hw] + beta[d] ----------------
// grid 1568 (32 b x 49 hw-tiles of 64), 256 thr. Thread (i,j): rows {4i,128+4i},
// cols {4j,32+4j} -> all LDS reads lane-contiguous float4s.
__global__ __launch_bounds__(256) void k_out(const float* __restrict__ X,
        const float* __restrict__ Mt, const float* __restrict__ weight,
        const float* __restrict__ beta, float* __restrict__ out) {
    __shared__ __align__(16) float Ms[32][260];  // Ms[kk][d] = M[d][c0+kk]
    __shared__ __align__(16) float xs[32][68];   // xs[kk][mm]
    const int tid = threadIdx.x;
    const int bk = blockIdx.x;
    const int b = bk / 49;
    const int hw0 = (bk - b * 49) * 64;
    const int i = tid >> 3, j = tid & 7;
    const float* Xb = X + (size_t)b * C_ * HW_ + hw0;
    float acc[8][8];
#pragma unroll
    for (int r = 0; r < 8; ++r)
#pragma unroll
        for (int s = 0; s < 8; ++s) acc[r][s] = 0.f;

    for (int c0 = 0; c0 < C_; c0 += 32) {
        __syncthreads();
#pragma unroll 4
        for (int s = 0; s < 32; ++s) Ms[s][tid] = Mt[(c0 + s) * 256 + tid];
#pragma unroll
        for (int s = 0; s < 8; ++s) {
            int idx = s * 256 + tid;
            int kk = idx >> 6, mm = idx & 63;
            xs[kk][mm] = Xb[(size_t)(c0 + kk) * HW_ + mm];
        }
        __syncthreads();
#pragma unroll 2
        for (int kk = 0; kk < 32; ++kk) {
            float a[8], bb[8];
            *(float4*)&a[0]  = *(const float4*)&Ms[kk][4 * i];
            *(float4*)&a[4]  = *(const float4*)&Ms[kk][128 + 4 * i];
            *(float4*)&bb[0] = *(const float4*)&xs[kk][4 * j];
            *(float4*)&bb[4] = *(const float4*)&xs[kk][32 + 4 * j];
#pragma unroll
            for (int r = 0; r < 8; ++r)
#pragma unroll
                for (int s = 0; s < 8; ++s) acc[r][s] += a[r] * bb[s];
        }
    }

    float* ob = out + (size_t)b * C_ * HW_ + hw0;
#pragma unroll
    for (int r = 0; r < 8; ++r) {
        int d = (r < 4) ? (4 * i + r) : (128 + 4 * i + r - 4);
        float w = weight[d], be = beta[d];
        float4 v0 = make_float4(w * acc[r][0] + be, w * acc[r][1] + be,
                                w * acc[r][2] + be, w * acc[r][3] + be);
        float4 v1 = make_float4(w * acc[r][4] + be, w * acc[r][5] + be,
                                w * acc[r][6] + be, w * acc[r][7] + be);
        *(float4*)&ob[(size_t)d * HW_ + 4 * j]      = v0;
        *(float4*)&ob[(size_t)d * HW_ + 32 + 4 * j] = v1;
    }
}

extern "C" void kernel_launch(void* const* d_in, const int* in_sizes, int n_in,
                              void* d_out, int out_size, void* d_ws, size_t ws_size,
                              hipStream_t stream) {
    const float* X      = (const float*)d_in[0];
    const float* rot    = (const float*)d_in[1];
    const float* weight = (const float*)d_in[2];
    const float* bias   = (const float*)d_in[3];
    float* out = (float*)d_out;
    float* wsf = (float*)d_ws;

    float* SigN = wsf;
    float* P    = wsf + 65536;
    float* P2   = wsf + 2 * 65536;
    float* Q    = wsf + 3 * 65536;
    float* Mt   = wsf + 4 * 65536;
    float* mean = wsf + 5 * 65536;
    float* beta = mean + 256;
    float* scal = mean + 512;
    float* psum = mean + 768;

    long avail = (long)(ws_size / 4) - (5L * 65536 + 768);
    int NP = (int)(avail / (65536 + 512));
    int atomic_mode = 0;
    if (NP >= 256) {
        NP = 256;
    } else {
        if (NP < 1) NP = 1;
        atomic_mode = 1;
    }
    float* pdiag = psum + (size_t)NP * 256;
    float* pG    = pdiag + (size_t)NP * 256;

    if (atomic_mode) {
        hipMemsetAsync(psum, 0, ((size_t)NP * 512 + (size_t)NP * 65536) * 4, stream);
    }

    k_gram<<<256, 1024, 0, stream>>>(X, pG, psum, pdiag, NP, atomic_mode);
    k_stats<<<1, 256, 0, stream>>>(psum, pdiag, mean, scal, NP);
    k_sigma<<<64, 1024, 0, stream>>>(pG, mean, scal, SigN, P, NP);
    for (int it = 0; it < 4; ++it) {
        k_mm_pair<<<128, 256, 0, stream>>>(P, P, P2, P, SigN, Q);
        k_mm_upd<<<64, 256, 0, stream>>>(P2, Q, P);
    }
    k_mm_rot<<<64, 256, 0, stream>>>(rot, P, Mt, scal);
    k_beta<<<1, 256, 0, stream>>>(Mt, mean, weight, bias, beta);
    k_out<<<1568, 256, 0, stream>>>(X, Mt, weight, beta, out);
}

// Round 4
// 503.968 us; speedup vs baseline: 1.5034x; 1.4275x over previous
//
#include <hip/hip_runtime.h>

#define C_ 256
#define B_ 32
#define HW_ 3136
#define M_ 100352
#define NCHUNK_ 256
#define CHM_ 392
#define EPSV 1e-5f

typedef unsigned short ushort_t;
typedef unsigned int uint_t;
typedef __attribute__((ext_vector_type(8))) short short8v;
typedef __attribute__((ext_vector_type(16))) float f32x16;

__device__ __forceinline__ ushort_t bfhi(float v) {
    union { float f; uint_t u; } x; x.f = v;
    uint_t r = x.u + 0x7fffu + ((x.u >> 16) & 1u);
    return (ushort_t)(r >> 16);
}
__device__ __forceinline__ float bf2f(ushort_t b) {
    union { uint_t u; float f; } x; x.u = ((uint_t)b) << 16;
    return x.f;
}
__device__ __forceinline__ void bsplit(float v, ushort_t& h, ushort_t& l) {
    h = bfhi(v);
    l = bfhi(v - bf2f(h));
}

// ---------------- K1: partial Gram via 3-term bf16-split MFMA ----------------
// grid 256 x 1024 thr (16 waves, 4x4 of 64x64 wave-tiles, 2x2 mfma_32x32x16 each).
// LDS rows 40 bf16 (80 B): 2-way bank aliasing only (free).
__global__ __launch_bounds__(1024) void k_gram(const float* __restrict__ X,
        float* __restrict__ pG, float* __restrict__ psum, float* __restrict__ pdiag,
        int NP, int atomic_mode) {
    __shared__ ushort_t xh[256 * 40];
    __shared__ ushort_t xl[256 * 40];
    __shared__ float red[1024];
    const int tid = threadIdx.x;
    const int wid = tid >> 6, lane = tid & 63;
    const int wr = wid >> 2, wc = wid & 3;
    const int lr = lane & 31, khalf = lane >> 5;
    const int sc = tid >> 2, skq = tid & 3;   // staging: channel, k-quarter (8 k each)

    f32x16 acc[2][2];
#pragma unroll
    for (int ti = 0; ti < 2; ++ti)
#pragma unroll
        for (int tj = 0; tj < 2; ++tj)
#pragma unroll
            for (int r = 0; r < 16; ++r) acc[ti][tj][r] = 0.f;

    float csum = 0.f, cdiag = 0.f;

    const int chunk = blockIdx.x;
    const int b = chunk >> 3;
    const int hw0 = (chunk & 7) * CHM_;
    const float* Xb = X + (size_t)b * C_ * HW_ + hw0 + (size_t)sc * HW_ + 8 * skq;

    float4 cv0, cv1;
    {   // prologue load k0=0 (klen>=32 always at k0=0)
        cv0 = *(const float4*)(Xb);
        cv1 = *(const float4*)(Xb + 4);
    }

    for (int k0 = 0; k0 < CHM_; k0 += 32) {
        // ---- convert + LDS write of current regs ----
        float va[8] = {cv0.x, cv0.y, cv0.z, cv0.w, cv1.x, cv1.y, cv1.z, cv1.w};
        ushort_t h[8], l[8];
#pragma unroll
        for (int e = 0; e < 8; ++e) {
            csum += va[e]; cdiag += va[e] * va[e];
            bsplit(va[e], h[e], l[e]);
        }
        uint4 H, L;
        H.x = (uint_t)h[0] | ((uint_t)h[1] << 16); H.y = (uint_t)h[2] | ((uint_t)h[3] << 16);
        H.z = (uint_t)h[4] | ((uint_t)h[5] << 16); H.w = (uint_t)h[6] | ((uint_t)h[7] << 16);
        L.x = (uint_t)l[0] | ((uint_t)l[1] << 16); L.y = (uint_t)l[2] | ((uint_t)l[3] << 16);
        L.z = (uint_t)l[4] | ((uint_t)l[5] << 16); L.w = (uint_t)l[6] | ((uint_t)l[7] << 16);
        const int sel = sc * 40 + 8 * skq;
        *(uint4*)&xh[sel] = H;
        *(uint4*)&xl[sel] = L;
        __syncthreads();

        // ---- issue next chunk's global loads (overlap with MFMA below) ----
        float4 nv0 = make_float4(0, 0, 0, 0), nv1 = nv0;
        const int kn = k0 + 32;
        if (kn < CHM_) {
            int klen = CHM_ - kn; if (klen > 32) klen = 32;
            if (8 * skq + 8 <= klen) {
                nv0 = *(const float4*)(Xb + kn);
                nv1 = *(const float4*)(Xb + kn + 4);
            }
        }

        // ---- fragments + MFMA ----
#pragma unroll
        for (int ik = 0; ik < 2; ++ik) {
            short8v ah[2], al[2], bh[2], bl[2];
#pragma unroll
            for (int t = 0; t < 2; ++t) {
                const int ea = (64 * wr + 32 * t + lr) * 40 + 16 * ik + 8 * khalf;
                ah[t] = *(const short8v*)&xh[ea];
                al[t] = *(const short8v*)&xl[ea];
                const int eb = (64 * wc + 32 * t + lr) * 40 + 16 * ik + 8 * khalf;
                bh[t] = *(const short8v*)&xh[eb];
                bl[t] = *(const short8v*)&xl[eb];
            }
#pragma unroll
            for (int ti = 0; ti < 2; ++ti)
#pragma unroll
                for (int tj = 0; tj < 2; ++tj) {
                    acc[ti][tj] = __builtin_amdgcn_mfma_f32_32x32x16_bf16(ah[ti], bh[tj], acc[ti][tj], 0, 0, 0);
                    acc[ti][tj] = __builtin_amdgcn_mfma_f32_32x32x16_bf16(ah[ti], bl[tj], acc[ti][tj], 0, 0, 0);
                    acc[ti][tj] = __builtin_amdgcn_mfma_f32_32x32x16_bf16(al[ti], bh[tj], acc[ti][tj], 0, 0, 0);
                }
        }
        __syncthreads();
        cv0 = nv0; cv1 = nv1;
    }

    // ---- per-channel sum / sumsq reduce (4 staging threads per channel) ----
    const int p = atomic_mode ? (blockIdx.x % NP) : blockIdx.x;
    red[tid] = csum;
    __syncthreads();
    if (tid < C_) {
        float s = red[4 * tid] + red[4 * tid + 1] + red[4 * tid + 2] + red[4 * tid + 3];
        if (atomic_mode) atomicAdd(&psum[p * C_ + tid], s); else psum[p * C_ + tid] = s;
    }
    __syncthreads();
    red[tid] = cdiag;
    __syncthreads();
    if (tid < C_) {
        float s = red[4 * tid] + red[4 * tid + 1] + red[4 * tid + 2] + red[4 * tid + 3];
        if (atomic_mode) atomicAdd(&pdiag[p * C_ + tid], s); else pdiag[p * C_ + tid] = s;
    }

    // ---- partial-Gram writeout ----
    float* og = pG + (size_t)p * 65536;
#pragma unroll
    for (int ti = 0; ti < 2; ++ti)
#pragma unroll
        for (int tj = 0; tj < 2; ++tj)
#pragma unroll
            for (int r = 0; r < 16; ++r) {
                const int rl = (r & 3) + 8 * (r >> 2) + 4 * khalf;
                const int row = 64 * wr + 32 * ti + rl;
                const int col = 64 * wc + 32 * tj + lr;
                if (atomic_mode) atomicAdd(&og[row * 256 + col], acc[ti][tj][r]);
                else og[row * 256 + col] = acc[ti][tj][r];
            }
}

// ---------------- K2: mean, trace, rTr ----------------
__global__ __launch_bounds__(256) void k_stats(const float* __restrict__ psum,
        const float* __restrict__ pdiag, float* __restrict__ mean,
        float* __restrict__ scal, int NP) {
    __shared__ float red[256];
    const int c = threadIdx.x;
    float s = 0.f, d = 0.f;
    for (int p = 0; p < NP; ++p) { s += psum[p * C_ + c]; d += pdiag[p * C_ + c]; }
    const float mn = s * (1.f / (float)M_);
    mean[c] = mn;
    red[c] = d * (1.f / (float)M_) - mn * mn + EPSV;
    __syncthreads();
    for (int off = 128; off > 0; off >>= 1) {
        if (c < off) red[c] += red[c + off];
        __syncthreads();
    }
    if (c == 0) {
        float rTr = 1.f / red[0];
        scal[0] = rTr;
        scal[1] = sqrtf(rTr);
    }
}

// ---------------- K3: assemble Sigma_N and P1 ----------------
__global__ __launch_bounds__(1024) void k_sigma(const float* __restrict__ pG,
        const float* __restrict__ mean, const float* __restrict__ scal,
        float* __restrict__ SigN, float* __restrict__ P, int NP) {
    const int e = blockIdx.x * 1024 + threadIdx.x;
    const int r = e >> 8, c = e & 255;
    float s = 0.f;
    for (int p = 0; p < NP; ++p) s += pG[(size_t)p * 65536 + e];
    float sig = s * (1.f / (float)M_) - mean[r] * mean[c] + ((r == c) ? EPSV : 0.f);
    float sn = sig * scal[0];
    SigN[e] = sn;
    P[e] = ((r == c) ? 1.5f : 0.f) - 0.5f * sn;
}

// ---------------- small 256x256 fp32 matmul body (NS chain: tiny, launch-bound) ----
__device__ __forceinline__ void mm_body(const float* __restrict__ A,
        const float* __restrict__ Bm, int blk, int tid,
        float& a00, float& a01, float& a10, float& a11, int& row, int& col) {
    __shared__ __align__(16) float Ast[256][34];
    __shared__ __align__(16) float Bs[256][34];
    const int bi = blk >> 3, bj = blk & 7;
    const int i2 = tid >> 4, j2 = tid & 15;
#pragma unroll 4
    for (int s = 0; s < 32; ++s) {
        Ast[tid][s] = A[(32 * bi + s) * 256 + tid];
        int k = s * 8 + (tid >> 5), cc = tid & 31;
        Bs[k][cc] = Bm[k * 256 + 32 * bj + cc];
    }
    __syncthreads();
    a00 = 0.f; a01 = 0.f; a10 = 0.f; a11 = 0.f;
#pragma unroll 8
    for (int k = 0; k < 256; ++k) {
        float2 av = *(const float2*)&Ast[k][2 * i2];
        float2 bv = *(const float2*)&Bs[k][2 * j2];
        a00 += av.x * bv.x; a01 += av.x * bv.y;
        a10 += av.y * bv.x; a11 += av.y * bv.y;
    }
    row = 32 * bi + 2 * i2; col = 32 * bj + 2 * j2;
}

__global__ __launch_bounds__(256) void k_mm_pair(const float* __restrict__ A1,
        const float* __restrict__ B1, float* __restrict__ D1,
        const float* __restrict__ A2, const float* __restrict__ B2, float* __restrict__ D2) {
    const int second = blockIdx.x >> 6;
    const float* A = second ? A2 : A1;
    const float* Bm = second ? B2 : B1;
    float* D = second ? D2 : D1;
    float a00, a01, a10, a11; int row, col;
    mm_body(A, Bm, blockIdx.x & 63, threadIdx.x, a00, a01, a10, a11, row, col);
    D[row * 256 + col] = a00;       D[row * 256 + col + 1] = a01;
    D[(row + 1) * 256 + col] = a10; D[(row + 1) * 256 + col + 1] = a11;
}

__global__ __launch_bounds__(256) void k_mm_upd(const float* __restrict__ A,
        const float* __restrict__ Bm, float* __restrict__ P) {
    float a00, a01, a10, a11; int row, col;
    mm_body(A, Bm, blockIdx.x, threadIdx.x, a00, a01, a10, a11, row, col);
    int e0 = row * 256 + col, e1 = e0 + 256;
    P[e0]     = 1.5f * P[e0]     - 0.5f * a00;
    P[e0 + 1] = 1.5f * P[e0 + 1] - 0.5f * a01;
    P[e1]     = 1.5f * P[e1]     - 0.5f * a10;
    P[e1 + 1] = 1.5f * P[e1 + 1] - 0.5f * a11;
}

// final: M = sqrt(rTr)*rot*P, row-major [d][c], fp32 + bf16 hi/lo splits
__global__ __launch_bounds__(256) void k_mm_rotM(const float* __restrict__ A,
        const float* __restrict__ Bm, float* __restrict__ Mf,
        ushort_t* __restrict__ Mhi, ushort_t* __restrict__ Mlo,
        const float* __restrict__ scal) {
    float a00, a01, a10, a11; int row, col;
    mm_body(A, Bm, blockIdx.x, threadIdx.x, a00, a01, a10, a11, row, col);
    const float sc = scal[1];
    float v[4] = {sc * a00, sc * a01, sc * a10, sc * a11};
    int idx[4] = {row * 256 + col, row * 256 + col + 1, (row + 1) * 256 + col, (row + 1) * 256 + col + 1};
#pragma unroll
    for (int e = 0; e < 4; ++e) {
        Mf[idx[e]] = v[e];
        ushort_t h, l; bsplit(v[e], h, l);
        Mhi[idx[e]] = h; Mlo[idx[e]] = l;
    }
}

// ---------------- K6: beta[d] = bias[d] - weight[d]*(M·mean)[d] ----------------
__global__ __launch_bounds__(256) void k_beta(const float* __restrict__ Mf,
        const float* __restrict__ mean, const float* __restrict__ weight,
        const float* __restrict__ bias, float* __restrict__ beta) {
    const int d = threadIdx.x;
    float s = 0.f;
    for (int c = 0; c < C_; ++c) s += Mf[d * 256 + c] * mean[c];
    beta[d] = bias[d] - weight[d] * s;
}

// ---------------- K7: out = w*(M·x) + beta via 3-term bf16-split MFMA ----------------
// grid 1600 (= 32 b x 25 k-chunks(128, tail 64) x 2 d-halves), 256 thr (4 waves 2x2).
__global__ __launch_bounds__(256) void k_out(const float* __restrict__ X,
        const ushort_t* __restrict__ Mhi, const ushort_t* __restrict__ Mlo,
        const float* __restrict__ weight, const float* __restrict__ beta,
        float* __restrict__ out) {
    __shared__ ushort_t Mh[128 * 40], Ml[128 * 40];
    __shared__ ushort_t Xh[128 * 40], Xl[128 * 40];
    __shared__ float wb[256];
    const int tid = threadIdx.x;
    const int wid = tid >> 6, lane = tid & 63;
    const int wr = wid >> 1, wc = wid & 1;
    const int lr = lane & 31, khalf = lane >> 5;

    const int bk = blockIdx.x;
    const int dh = bk & 1;
    const int tmp = bk >> 1;
    const int b = tmp / 25, kc = tmp - b * 25;
    const int d0 = dh * 128;
    const int hw0 = kc * 128;
    int klim = HW_ - hw0; if (klim > 128) klim = 128;

    // staging maps
    const int md = tid >> 1, mh16 = tid & 1;          // M: 128 d-rows x 32 c
    const int cg = tid >> 5, kq = tid & 31;           // x: 4 channels x 4 k per thread

    if (tid < 128) { wb[tid] = weight[d0 + tid]; wb[128 + tid] = beta[d0 + tid]; }

    f32x16 acc[2][2];
#pragma unroll
    for (int ti = 0; ti < 2; ++ti)
#pragma unroll
        for (int tj = 0; tj < 2; ++tj)
#pragma unroll
            for (int r = 0; r < 16; ++r) acc[ti][tj][r] = 0.f;

    const float* Xp = X + (size_t)b * C_ * HW_ + hw0 + 4 * kq;
    const bool xvalid = (4 * kq + 4 <= klim);

    uint4 pmh0, pmh1, pml0, pml1;
    float4 pxv[4];
    {   // prologue: prefetch chunk 0
        const size_t mo = (size_t)(d0 + md) * 256 + 16 * mh16;
        pmh0 = *(const uint4*)&Mhi[mo]; pmh1 = *(const uint4*)&Mhi[mo + 8];
        pml0 = *(const uint4*)&Mlo[mo]; pml1 = *(const uint4*)&Mlo[mo + 8];
#pragma unroll
        for (int cc = 0; cc < 4; ++cc)
            pxv[cc] = xvalid ? *(const float4*)(Xp + (size_t)(4 * cg + cc) * HW_)
                             : make_float4(0, 0, 0, 0);
    }

    for (int step = 0; step < 8; ++step) {
        // ---- write current chunk to LDS ----
        {
            const int me = md * 40 + 16 * mh16;
            *(uint4*)&Mh[me] = pmh0; *(uint4*)&Mh[me + 8] = pmh1;
            *(uint4*)&Ml[me] = pml0; *(uint4*)&Ml[me + 8] = pml1;
            ushort_t hx[4][4], lx[4][4];
#pragma unroll
            for (int cc = 0; cc < 4; ++cc) {
                float vv[4] = {pxv[cc].x, pxv[cc].y, pxv[cc].z, pxv[cc].w};
#pragma unroll
                for (int e = 0; e < 4; ++e) bsplit(vv[e], hx[cc][e], lx[cc][e]);
            }
#pragma unroll
            for (int e = 0; e < 4; ++e) {
                uint2 uh, ul;
                uh.x = (uint_t)hx[0][e] | ((uint_t)hx[1][e] << 16);
                uh.y = (uint_t)hx[2][e] | ((uint_t)hx[3][e] << 16);
                ul.x = (uint_t)lx[0][e] | ((uint_t)lx[1][e] << 16);
                ul.y = (uint_t)lx[2][e] | ((uint_t)lx[3][e] << 16);
                const int xe = (4 * kq + e) * 40 + 4 * cg;
                *(uint2*)&Xh[xe] = uh;
                *(uint2*)&Xl[xe] = ul;
            }
        }
        __syncthreads();

        // ---- prefetch next chunk ----
        if (step < 7) {
            const int c0 = 32 * (step + 1);
            const size_t mo = (size_t)(d0 + md) * 256 + c0 + 16 * mh16;
            pmh0 = *(const uint4*)&Mhi[mo]; pmh1 = *(const uint4*)&Mhi[mo + 8];
            pml0 = *(const uint4*)&Mlo[mo]; pml1 = *(const uint4*)&Mlo[mo + 8];
#pragma unroll
            for (int cc = 0; cc < 4; ++cc)
                pxv[cc] = xvalid ? *(const float4*)(Xp + (size_t)(c0 + 4 * cg + cc) * HW_)
                                 : make_float4(0, 0, 0, 0);
        }

        // ---- fragments + MFMA ----
#pragma unroll
        for (int ik = 0; ik < 2; ++ik) {
            short8v ah[2], al2[2], bh[2], bl[2];
#pragma unroll
            for (int t = 0; t < 2; ++t) {
                const int ea = (64 * wr + 32 * t + lr) * 40 + 16 * ik + 8 * khalf;
                ah[t]  = *(const short8v*)&Mh[ea];
                al2[t] = *(const short8v*)&Ml[ea];
                const int eb = (64 * wc + 32 * t + lr) * 40 + 16 * ik + 8 * khalf;
                bh[t] = *(const short8v*)&Xh[eb];
                bl[t] = *(const short8v*)&Xl[eb];
            }
#pragma unroll
            for (int ti = 0; ti < 2; ++ti)
#pragma unroll
                for (int tj = 0; tj < 2; ++tj) {
                    acc[ti][tj] = __builtin_amdgcn_mfma_f32_32x32x16_bf16(ah[ti],  bh[tj], acc[ti][tj], 0, 0, 0);
                    acc[ti][tj] = __builtin_amdgcn_mfma_f32_32x32x16_bf16(ah[ti],  bl[tj], acc[ti][tj], 0, 0, 0);
                    acc[ti][tj] = __builtin_amdgcn_mfma_f32_32x32x16_bf16(al2[ti], bh[tj], acc[ti][tj], 0, 0, 0);
                }
        }
        __syncthreads();
    }

    // ---- store with affine ----
#pragma unroll
    for (int ti = 0; ti < 2; ++ti)
#pragma unroll
        for (int tj = 0; tj < 2; ++tj)
#pragma unroll
            for (int r = 0; r < 16; ++r) {
                const int rl = (r & 3) + 8 * (r >> 2) + 4 * khalf;
                const int dl = 64 * wr + 32 * ti + rl;
                const int col = 64 * wc + 32 * tj + lr;
                if (col < klim) {
                    out[((size_t)b * C_ + d0 + dl) * HW_ + hw0 + col] =
                        wb[dl] * acc[ti][tj][r] + wb[128 + dl];
                }
            }
}

extern "C" void kernel_launch(void* const* d_in, const int* in_sizes, int n_in,
                              void* d_out, int out_size, void* d_ws, size_t ws_size,
                              hipStream_t stream) {
    const float* X      = (const float*)d_in[0];
    const float* rot    = (const float*)d_in[1];
    const float* weight = (const float*)d_in[2];
    const float* bias   = (const float*)d_in[3];
    float* out = (float*)d_out;
    float* wsf = (float*)d_ws;

    float* SigN = wsf;
    float* P    = wsf + 65536;
    float* P2   = wsf + 2 * 65536;
    float* Q    = wsf + 3 * 65536;
    float* Mf   = wsf + 4 * 65536;
    ushort_t* Mhi = (ushort_t*)(wsf + 5 * 65536);
    ushort_t* Mlo = (ushort_t*)(wsf + 5 * 65536 + 32768);
    float* mean = wsf + 6 * 65536;
    float* beta = mean + 256;
    float* scal = mean + 512;
    float* psum = mean + 768;

    long avail = (long)(ws_size / 4) - (6L * 65536 + 768);
    int NP = (int)(avail / (65536 + 512));
    int atomic_mode = 0;
    if (NP >= 256) {
        NP = 256;
    } else {
        if (NP < 1) NP = 1;
        atomic_mode = 1;
    }
    float* pdiag = psum + (size_t)NP * 256;
    float* pG    = pdiag + (size_t)NP * 256;

    if (atomic_mode) {
        hipMemsetAsync(psum, 0, ((size_t)NP * 512 + (size_t)NP * 65536) * 4, stream);
    }

    k_gram<<<256, 1024, 0, stream>>>(X, pG, psum, pdiag, NP, atomic_mode);
    k_stats<<<1, 256, 0, stream>>>(psum, pdiag, mean, scal, NP);
    k_sigma<<<64, 1024, 0, stream>>>(pG, mean, scal, SigN, P, NP);
    for (int it = 0; it < 4; ++it) {
        k_mm_pair<<<128, 256, 0, stream>>>(P, P, P2, P, SigN, Q);
        k_mm_upd<<<64, 256, 0, stream>>>(P2, Q, P);
    }
    k_mm_rotM<<<64, 256, 0, stream>>>(rot, P, Mf, Mhi, Mlo, scal);
    k_beta<<<1, 256, 0, stream>>>(Mf, mean, weight, bias, beta);
    k_out<<<1600, 256, 0, stream>>>(X, Mhi, Mlo, weight, beta, out);
}

// Round 9
// 424.979 us; speedup vs baseline: 1.7828x; 1.1859x over previous
//
#include <hip/hip_runtime.h>

#define C_ 256
#define B_ 32
#define HW_ 3136
#define M_ 100352
#define EPSV 1e-5f
#define GBLK 224
#define GCH 7          // 224 * 7 * 64 = 100352 = M_  (exact)
#define NPART 1568     // 32 b * 49 hw-tiles

typedef unsigned short ushort_t;
typedef unsigned int uint_t;
typedef __attribute__((ext_vector_type(8))) short short8v;
typedef __attribute__((ext_vector_type(16))) float f32x16;

__device__ __forceinline__ ushort_t bfhi(float v) {
    union { float f; uint_t u; } x; x.f = v;
    uint_t r = x.u + 0x7fffu + ((x.u >> 16) & 1u);
    return (ushort_t)(r >> 16);
}
__device__ __forceinline__ float bf2f(ushort_t b) {
    union { uint_t u; float f; } x; x.u = ((uint_t)b) << 16;
    return x.f;
}
__device__ __forceinline__ void bsplit(float v, ushort_t& h, ushort_t& l) {
    h = bfhi(v);
    l = bfhi(v - bf2f(h));
}

// async global->LDS, 16B per lane; lds dest must be wave-uniform base (HW adds lane*16)
__device__ __forceinline__ void gl_lds16(const void* g, void* l) {
    __builtin_amdgcn_global_load_lds(
        (const __attribute__((address_space(1))) unsigned int*)g,
        (__attribute__((address_space(3))) unsigned int*)l, 16, 0, 0);
}

// ---------------- K0: split X -> bf16 hi/lo in [c][m] layout (+ per-channel partials) ----
// grid (49 hwg, 32 b, 8 cg) x 256 thr. Thread: 1 channel, 8 strided hw elems.
// Partials written non-atomically: psum[(b*49+hwg)*256 + c].
__global__ __launch_bounds__(256) void k_split(const float* __restrict__ X,
        ushort_t* __restrict__ Xh, ushort_t* __restrict__ Xl,
        float* __restrict__ psum, float* __restrict__ pdiag) {
    const int tid = threadIdx.x;
    const int c_l = tid >> 3, h = tid & 7;
    const int c = blockIdx.z * 32 + c_l;
    const int hw = blockIdx.x * 64 + h * 8;
    const float* src = X + ((size_t)(blockIdx.y * C_ + c) * HW_ + hw);
    float4 v0 = *(const float4*)src;
    float4 v1 = *(const float4*)(src + 4);
    float va[8] = {v0.x, v0.y, v0.z, v0.w, v1.x, v1.y, v1.z, v1.w};
    ushort_t hh[8], ll[8];
    float s = 0.f, q = 0.f;
#pragma unroll
    for (int e = 0; e < 8; ++e) {
        s += va[e]; q += va[e] * va[e];
        bsplit(va[e], hh[e], ll[e]);
    }
    uint4 H, L;
    H.x = (uint_t)hh[0] | ((uint_t)hh[1] << 16); H.y = (uint_t)hh[2] | ((uint_t)hh[3] << 16);
    H.z = (uint_t)hh[4] | ((uint_t)hh[5] << 16); H.w = (uint_t)hh[6] | ((uint_t)hh[7] << 16);
    L.x = (uint_t)ll[0] | ((uint_t)ll[1] << 16); L.y = (uint_t)ll[2] | ((uint_t)ll[3] << 16);
    L.z = (uint_t)ll[4] | ((uint_t)ll[5] << 16); L.w = (uint_t)ll[6] | ((uint_t)ll[7] << 16);
    const size_t o = (size_t)c * M_ + (size_t)blockIdx.y * HW_ + hw;
    *(uint4*)&Xh[o] = H;
    *(uint4*)&Xl[o] = L;
#pragma unroll
    for (int off = 1; off < 8; off <<= 1) {
        s += __shfl_xor(s, off);
        q += __shfl_xor(q, off);
    }
    if (h == 0) {
        const int p = blockIdx.y * 49 + blockIdx.x;
        psum[p * C_ + c] = s;
        pdiag[p * C_ + c] = q;
    }
}

// ---------------- K1: Gram via 3-term bf16-split MFMA, global_load_lds staging ----
// 224 blocks x 1024 thr (16 waves 4x4). Chunk = 64 m; 7 chunks/block; dbl-buffered.
// LDS rows = 64 bf16 (128 B), XOR-swizzled 16B chunks: slot q holds global chunk q^(row&7).
__global__ __launch_bounds__(1024) void k_gram(const ushort_t* __restrict__ Xh,
        const ushort_t* __restrict__ Xl, float* __restrict__ pG) {
    __shared__ ushort_t buf[2][2][C_ * 64];   // [dbuf][hi/lo][c][64]  = 128 KB
    const int tid = threadIdx.x;
    const int wid = tid >> 6, lane = tid & 63;
    const int wr = wid >> 2, wc = wid & 3;
    const int lr = lane & 31, khalf = lane >> 5;
    const int sr = lane >> 3, sq = lane & 7;

    f32x16 acc[2][2];
#pragma unroll
    for (int ti = 0; ti < 2; ++ti)
#pragma unroll
        for (int tj = 0; tj < 2; ++tj)
#pragma unroll
            for (int r = 0; r < 16; ++r) acc[ti][tj][r] = 0.f;

    const int chunk0 = blockIdx.x * GCH;

    auto stage = [&](int bb, int ch) {
        const size_t m0 = (size_t)ch * 64;
#pragma unroll
        for (int s = 0; s < 2; ++s) {
            const ushort_t* src = s ? Xl : Xh;
#pragma unroll
            for (int i = 0; i < 2; ++i) {
                const int r0 = wid * 16 + i * 8;
                const int r = r0 + sr;
                gl_lds16(src + (size_t)r * M_ + m0 + 8 * (sq ^ (r & 7)),
                         &buf[bb][s][r0 * 64]);
            }
        }
    };

    auto compute = [&](int bb) {
#pragma unroll
        for (int ik = 0; ik < 4; ++ik) {
            const int q0 = 2 * ik + khalf;
            short8v ah[2], al[2], bh[2], bl[2];
#pragma unroll
            for (int t = 0; t < 2; ++t) {
                const int ra = 64 * wr + 32 * t + lr;
                const int ia = ra * 64 + 8 * (q0 ^ (ra & 7));
                ah[t] = *(const short8v*)&buf[bb][0][ia];
                al[t] = *(const short8v*)&buf[bb][1][ia];
                const int rb = 64 * wc + 32 * t + lr;
                const int ib = rb * 64 + 8 * (q0 ^ (rb & 7));
                bh[t] = *(const short8v*)&buf[bb][0][ib];
                bl[t] = *(const short8v*)&buf[bb][1][ib];
            }
#pragma unroll
            for (int ti = 0; ti < 2; ++ti)
#pragma unroll
                for (int tj = 0; tj < 2; ++tj) {
                    acc[ti][tj] = __builtin_amdgcn_mfma_f32_32x32x16_bf16(ah[ti], bh[tj], acc[ti][tj], 0, 0, 0);
                    acc[ti][tj] = __builtin_amdgcn_mfma_f32_32x32x16_bf16(ah[ti], bl[tj], acc[ti][tj], 0, 0, 0);
                    acc[ti][tj] = __builtin_amdgcn_mfma_f32_32x32x16_bf16(al[ti], bh[tj], acc[ti][tj], 0, 0, 0);
                }
        }
    };

    stage(0, chunk0);
    for (int t = 0; t < GCH; ++t) {
        __syncthreads();                         // drains in-flight gl_lds for buf[t&1]
        if (t + 1 < GCH) stage((t + 1) & 1, chunk0 + t + 1);
        compute(t & 1);
    }

    float* og = pG + (size_t)blockIdx.x * 65536;
#pragma unroll
    for (int ti = 0; ti < 2; ++ti)
#pragma unroll
        for (int tj = 0; tj < 2; ++tj)
#pragma unroll
            for (int r = 0; r < 16; ++r) {
                const int rl = (r & 3) + 8 * (r >> 2) + 4 * khalf;
                const int row = 64 * wr + 32 * ti + rl;
                const int col = 64 * wc + 32 * tj + lr;
                og[row * 256 + col] = acc[ti][tj][r];
            }
}

// ---------------- K1b: fold 32 b-partials per hw-tile group (49 blocks) ----------------
__global__ __launch_bounds__(256) void k_red1(const float* __restrict__ psum,
        const float* __restrict__ pdiag, float* __restrict__ rsum,
        float* __restrict__ rdiag) {
    const int c = threadIdx.x, g = blockIdx.x;   // g in 0..48
    float s = 0.f, d = 0.f;
#pragma unroll 4
    for (int b = 0; b < 32; ++b) {
        const size_t p = (size_t)(b * 49 + g) * C_ + c;
        s += psum[p];
        d += pdiag[p];
    }
    rsum[g * C_ + c] = s;
    rdiag[g * C_ + c] = d;
}

// ---------------- K2: mean, trace, rTr (reduce 49 partials) ----------------
__global__ __launch_bounds__(256) void k_stats(const float* __restrict__ rsum,
        const float* __restrict__ rdiag, float* __restrict__ mean,
        float* __restrict__ scal) {
    __shared__ float red[256];
    const int c = threadIdx.x;
    float s = 0.f, d = 0.f;
#pragma unroll 7
    for (int p = 0; p < 49; ++p) {
        s += rsum[p * C_ + c];
        d += rdiag[p * C_ + c];
    }
    const float mn = s * (1.f / (float)M_);
    mean[c] = mn;
    red[c] = d * (1.f / (float)M_) - mn * mn + EPSV;
    __syncthreads();
    for (int off = 128; off > 0; off >>= 1) {
        if (c < off) red[c] += red[c + off];
        __syncthreads();
    }
    if (c == 0) {
        float rTr = 1.f / red[0];
        scal[0] = rTr;
        scal[1] = sqrtf(rTr);
    }
}

// ---------------- K3: assemble Sigma_N and P1 ----------------
__global__ __launch_bounds__(256) void k_sigma(const float* __restrict__ pG,
        const float* __restrict__ mean, const float* __restrict__ scal,
        float* __restrict__ SigN, float* __restrict__ P) {
    const int e = blockIdx.x * 256 + threadIdx.x;
    const int r = e >> 8, c = e & 255;
    float s = 0.f;
    for (int p = 0; p < GBLK; p += 4) {
        s += pG[(size_t)p * 65536 + e] + pG[(size_t)(p + 1) * 65536 + e]
           + pG[(size_t)(p + 2) * 65536 + e] + pG[(size_t)(p + 3) * 65536 + e];
    }
    float sig = s * (1.f / (float)M_) - mean[r] * mean[c] + ((r == c) ? EPSV : 0.f);
    float sn = sig * scal[0];
    SigN[e] = sn;
    P[e] = ((r == c) ? 1.5f : 0.f) - 0.5f * sn;
}

// ---------------- small 256x256 fp32 matmul (NS chain) ----------------
__device__ __forceinline__ void mm_body(const float* __restrict__ A,
        const float* __restrict__ Bm, int blk, int tid,
        float& a00, float& a01, float& a10, float& a11, int& row, int& col) {
    __shared__ __align__(16) float Ast[256][34];
    __shared__ __align__(16) float Bs[256][34];
    const int bi = blk >> 3, bj = blk & 7;
    const int i2 = tid >> 4, j2 = tid & 15;
#pragma unroll 4
    for (int s = 0; s < 32; ++s) {
        Ast[tid][s] = A[(32 * bi + s) * 256 + tid];
        int k = s * 8 + (tid >> 5), cc = tid & 31;
        Bs[k][cc] = Bm[k * 256 + 32 * bj + cc];
    }
    __syncthreads();
    a00 = 0.f; a01 = 0.f; a10 = 0.f; a11 = 0.f;
#pragma unroll 8
    for (int k = 0; k < 256; ++k) {
        float2 av = *(const float2*)&Ast[k][2 * i2];
        float2 bv = *(const float2*)&Bs[k][2 * j2];
        a00 += av.x * bv.x; a01 += av.x * bv.y;
        a10 += av.y * bv.x; a11 += av.y * bv.y;
    }
    row = 32 * bi + 2 * i2; col = 32 * bj + 2 * j2;
}

__global__ __launch_bounds__(256) void k_mm_pair(const float* __restrict__ A1,
        const float* __restrict__ B1, float* __restrict__ D1,
        const float* __restrict__ A2, const float* __restrict__ B2, float* __restrict__ D2) {
    const int second = blockIdx.x >> 6;
    const float* A = second ? A2 : A1;
    const float* Bm = second ? B2 : B1;
    float* D = second ? D2 : D1;
    float a00, a01, a10, a11; int row, col;
    mm_body(A, Bm, blockIdx.x & 63, threadIdx.x, a00, a01, a10, a11, row, col);
    D[row * 256 + col] = a00;       D[row * 256 + col + 1] = a01;
    D[(row + 1) * 256 + col] = a10; D[(row + 1) * 256 + col + 1] = a11;
}

__global__ __launch_bounds__(256) void k_mm_upd(const float* __restrict__ A,
        const float* __restrict__ Bm, float* __restrict__ P) {
    float a00, a01, a10, a11; int row, col;
    mm_body(A, Bm, blockIdx.x, threadIdx.x, a00, a01, a10, a11, row, col);
    int e0 = row * 256 + col, e1 = e0 + 256;
    P[e0]     = 1.5f * P[e0]     - 0.5f * a00;
    P[e0 + 1] = 1.5f * P[e0 + 1] - 0.5f * a01;
    P[e1]     = 1.5f * P[e1]     - 0.5f * a10;
    P[e1 + 1] = 1.5f * P[e1 + 1] - 0.5f * a11;
}

// final: M = sqrt(rTr)*rot*P, row-major [d][c], fp32 + bf16 hi/lo splits
__global__ __launch_bounds__(256) void k_mm_rotM(const float* __restrict__ A,
        const float* __restrict__ Bm, float* __restrict__ Mf,
        ushort_t* __restrict__ Mhi, ushort_t* __restrict__ Mlo,
        const float* __restrict__ scal) {
    float a00, a01, a10, a11; int row, col;
    mm_body(A, Bm, blockIdx.x, threadIdx.x, a00, a01, a10, a11, row, col);
    const float sc = scal[1];
    float v[4] = {sc * a00, sc * a01, sc * a10, sc * a11};
    int idx[4] = {row * 256 + col, row * 256 + col + 1, (row + 1) * 256 + col, (row + 1) * 256 + col + 1};
#pragma unroll
    for (int e = 0; e < 4; ++e) {
        Mf[idx[e]] = v[e];
        ushort_t h, l; bsplit(v[e], h, l);
        Mhi[idx[e]] = h; Mlo[idx[e]] = l;
    }
}

// ---------------- K6: beta[d] = bias[d] - weight[d]*(M·mean)[d] ----------------
__global__ __launch_bounds__(256) void k_beta(const float* __restrict__ Mf,
        const float* __restrict__ mean, const float* __restrict__ weight,
        const float* __restrict__ bias, float* __restrict__ beta) {
    const int d = threadIdx.x;
    float s = 0.f;
    for (int c = 0; c < C_; ++c) s += Mf[d * 256 + c] * mean[c];
    beta[d] = bias[d] - weight[d] * s;
}

// ---------------- K7: out = w*(M·x)+beta, 3-term split MFMA ----------------
// grid (49 hwg, 32 b) x 256 thr (4 waves; wave w = d rows 64w..64w+64, hw tile 64).
// K-chunks of 64 c. M via global_load_lds (pre-split, swizzled src); X fp32 reg-split
// with conflict-free swizzled transpose writes. LDS rows 128 B + XOR swizzle.
__global__ __launch_bounds__(256) void k_out(const float* __restrict__ X,
        const ushort_t* __restrict__ Mhi, const ushort_t* __restrict__ Mlo,
        const float* __restrict__ weight, const float* __restrict__ beta,
        float* __restrict__ out) {
    __shared__ ushort_t Mh[C_ * 64], Ml[C_ * 64];   // 32 KB each
    __shared__ ushort_t Th[64 * 64], Tl[64 * 64];   // 8 KB each
    const int tid = threadIdx.x;
    const int wid = tid >> 6, lane = tid & 63;
    const int lr = lane & 31, khalf = lane >> 5;
    const int sr = lane >> 3, sq = lane & 7;
    const int cpair = tid >> 3, h = tid & 7;
    const int hw0 = blockIdx.x * 64;
    const int b = blockIdx.y;

    f32x16 acc[2][2];
#pragma unroll
    for (int ti = 0; ti < 2; ++ti)
#pragma unroll
        for (int tj = 0; tj < 2; ++tj)
#pragma unroll
            for (int r = 0; r < 16; ++r) acc[ti][tj][r] = 0.f;

    const float* Xb = X + (size_t)(b * C_) * HW_ + hw0;

    for (int c0 = 0; c0 < C_; c0 += 64) {
        // fp32 X loads for this chunk (issued before barrier; latency overlaps)
        const int ca = c0 + 2 * cpair;
        float xa[2][8];
#pragma unroll
        for (int e = 0; e < 8; ++e) {
            xa[0][e] = Xb[(size_t)ca * HW_ + h + 8 * e];
            xa[1][e] = Xb[(size_t)(ca + 1) * HW_ + h + 8 * e];
        }
        __syncthreads();   // previous chunk's MFMA done before LDS overwrite
        // M tile via global_load_lds (src pre-swizzled)
#pragma unroll
        for (int s = 0; s < 2; ++s) {
            const ushort_t* msrc = s ? Mlo : Mhi;
            ushort_t* mdst = s ? Ml : Mh;
#pragma unroll
            for (int i = 0; i < 8; ++i) {
                const int r0 = wid * 64 + i * 8;
                const int r = r0 + sr;
                gl_lds16(msrc + (size_t)r * C_ + c0 + 8 * (sq ^ (r & 7)), &mdst[r0 * 64]);
            }
        }
        // X transpose+split: row=hw (row&7 = h varies per lane -> conflict-free writes)
#pragma unroll
        for (int e = 0; e < 8; ++e) {
            const int row = h + 8 * e;
            ushort_t h0, l0, h1, l1;
            bsplit(xa[0][e], h0, l0);
            bsplit(xa[1][e], h1, l1);
            const int ui = row * 64 + 8 * ((cpair >> 2) ^ h) + 2 * (cpair & 3);
            *(uint_t*)&Th[ui] = (uint_t)h0 | ((uint_t)h1 << 16);
            *(uint_t*)&Tl[ui] = (uint_t)l0 | ((uint_t)l1 << 16);
        }
        __syncthreads();   // drains gl_lds (vmcnt) + ds_writes (lgkm)
#pragma unroll
        for (int ik = 0; ik < 4; ++ik) {
            const int q0 = 2 * ik + khalf;
            short8v ah[2], am[2], bh[2], bl[2];
#pragma unroll
            for (int t = 0; t < 2; ++t) {
                const int ra = 64 * wid + 32 * t + lr;
                const int ia = ra * 64 + 8 * (q0 ^ (ra & 7));
                ah[t] = *(const short8v*)&Mh[ia];
                am[t] = *(const short8v*)&Ml[ia];
                const int rb = 32 * t + lr;
                const int ib = rb * 64 + 8 * (q0 ^ (rb & 7));
                bh[t] = *(const short8v*)&Th[ib];
                bl[t] = *(const short8v*)&Tl[ib];
            }
#pragma unroll
            for (int ti = 0; ti < 2; ++ti)
#pragma unroll
                for (int tj = 0; tj < 2; ++tj) {
                    acc[ti][tj] = __builtin_amdgcn_mfma_f32_32x32x16_bf16(ah[ti], bh[tj], acc[ti][tj], 0, 0, 0);
                    acc[ti][tj] = __builtin_amdgcn_mfma_f32_32x32x16_bf16(ah[ti], bl[tj], acc[ti][tj], 0, 0, 0);
                    acc[ti][tj] = __builtin_amdgcn_mfma_f32_32x32x16_bf16(am[ti], bh[tj], acc[ti][tj], 0, 0, 0);
                }
        }
    }

#pragma unroll
    for (int ti = 0; ti < 2; ++ti)
#pragma unroll
        for (int tj = 0; tj < 2; ++tj)
#pragma unroll
            for (int r = 0; r < 16; ++r) {
                const int rl = (r & 3) + 8 * (r >> 2) + 4 * khalf;
                const int d = 64 * wid + 32 * ti + rl;
                const int col = 32 * tj + lr;
                out[((size_t)(b * C_ + d)) * HW_ + hw0 + col] =
                    weight[d] * acc[ti][tj][r] + beta[d];
            }
}

extern "C" void kernel_launch(void* const* d_in, const int* in_sizes, int n_in,
                              void* d_out, int out_size, void* d_ws, size_t ws_size,
                              hipStream_t stream) {
    const float* X      = (const float*)d_in[0];
    const float* rot    = (const float*)d_in[1];
    const float* weight = (const float*)d_in[2];
    const float* bias   = (const float*)d_in[3];
    float* out = (float*)d_out;
    float* wsf = (float*)d_ws;

    // bf16 split of X lives in d_out (read only by k_gram, before k_out writes out)
    ushort_t* Xh = (ushort_t*)d_out;
    ushort_t* Xl = Xh + (size_t)C_ * M_;

    float* SigN = wsf;
    float* P    = wsf + 65536;
    float* P2   = wsf + 2 * 65536;
    float* Q    = wsf + 3 * 65536;
    float* Mf   = wsf + 4 * 65536;
    ushort_t* Mhi = (ushort_t*)(wsf + 5 * 65536);
    ushort_t* Mlo = Mhi + 65536;
    float* small = wsf + 6 * 65536;
    float* mean  = small;
    float* betav = small + 256;
    float* scal  = small + 512;
    float* psum  = small + 1024;                      // NPART*256
    float* pdiag = psum + (size_t)NPART * C_;         // NPART*256
    float* rsum  = pdiag + (size_t)NPART * C_;        // 49*256
    float* rdiag = rsum + 49 * C_;                    // 49*256
    float* pG    = rdiag + 49 * C_;                   // 224 * 65536

    k_split<<<dim3(49, 32, 8), 256, 0, stream>>>(X, Xh, Xl, psum, pdiag);
    k_gram<<<GBLK, 1024, 0, stream>>>(Xh, Xl, pG);
    k_red1<<<49, 256, 0, stream>>>(psum, pdiag, rsum, rdiag);
    k_stats<<<1, 256, 0, stream>>>(rsum, rdiag, mean, scal);
    k_sigma<<<256, 256, 0, stream>>>(pG, mean, scal, SigN, P);
    for (int it = 0; it < 4; ++it) {
        k_mm_pair<<<128, 256, 0, stream>>>(P, P, P2, P, SigN, Q);
        k_mm_upd<<<64, 256, 0, stream>>>(P2, Q, P);
    }
    k_mm_rotM<<<64, 256, 0, stream>>>(rot, P, Mf, Mhi, Mlo, scal);
    k_beta<<<1, 256, 0, stream>>>(Mf, mean, weight, bias, betav);
    k_out<<<dim3(49, 32), 256, 0, stream>>>(X, Mhi, Mlo, weight, betav, out);
}